// Round 15
// baseline (2751.163 us; speedup 1.0000x reference)
//
#include <hip/hip_runtime.h>
#include <math.h>

#define H 512
#define V 5000
#define BB 128
#define SS 64
#define TT 52

typedef __attribute__((ext_vector_type(8))) short bf16x8;
typedef __attribute__((ext_vector_type(4))) float f32x4;
typedef __attribute__((ext_vector_type(2))) float f32x2;

__device__ __forceinline__ unsigned short f2b(float f) {
    unsigned u = __float_as_uint(f);
    return (unsigned short)((u + 0x7fffu + ((u >> 16) & 1u)) >> 16);
}
__device__ __forceinline__ float b2f(unsigned short u) {
    return __uint_as_float((unsigned)u << 16);
}
__device__ __forceinline__ float ftanh(float x) {
    return 1.f - 2.f / (1.f + __expf(2.f * x));
}
__device__ __forceinline__ float fsig(float x) {
    return 1.f / (1.f + __expf(-x));
}
__device__ __forceinline__ unsigned char f2fp8(float f) {
    return (unsigned char)__builtin_amdgcn_cvt_pk_fp8_f32(f, f, 0, 0);
}

// ---------------------------------------------------------------------------
// prep: WT8p [128][2560] u32 = fp8-packed TRANSPOSED recurrent weights:
// WT8p[k4][j] packs W[j][4k4..4k4+3] where W = [Wa ; W_hh]  (lane-consecutive
// j => coalesced GEMV reads; 1.31MB => L2-resident per XCD).
// Wxb [2048][512] = W_ih[:, :512] bf16 (xgates GEMM), Wc = W_ih[:, 512:],
// bbig = [ba ; b_ih+b_hh], bf16 Ua/Wout/enc.
// ---------------------------------------------------------------------------
__global__ __launch_bounds__(256)
void prep_w(const float* __restrict__ Wa, const float* __restrict__ Whh,
            const float* __restrict__ Wih,
            const float* __restrict__ ba, const float* __restrict__ bih,
            const float* __restrict__ bhh,
            const float* __restrict__ Ua, const float* __restrict__ Wout,
            const float* __restrict__ enc,
            unsigned* __restrict__ WT8p, unsigned short* __restrict__ Wxb,
            unsigned short* __restrict__ Wc,
            unsigned short* __restrict__ Uab, unsigned short* __restrict__ Woutb,
            unsigned short* __restrict__ encb, float* __restrict__ bbig)
{
    const int stride = gridDim.x * blockDim.x;
    const int t0 = blockIdx.x * blockDim.x + threadIdx.x;
    for (int idx = t0; idx < 128 * 2560; idx += stride) {
        const int k4 = idx / 2560;
        const int j  = idx - k4 * 2560;
        const int k  = k4 * 4;
        float w0, w1, w2, w3;
        if (j < H) {
            w0 = Wa[j * H + k];     w1 = Wa[j * H + k + 1];
            w2 = Wa[j * H + k + 2]; w3 = Wa[j * H + k + 3];
        } else {
            const int n = j - H;
            w0 = Whh[n * H + k];     w1 = Whh[n * H + k + 1];
            w2 = Whh[n * H + k + 2]; w3 = Whh[n * H + k + 3];
        }
        unsigned v = __builtin_amdgcn_cvt_pk_fp8_f32(w0, w1, 0u, 0);
        v = __builtin_amdgcn_cvt_pk_fp8_f32(w2, w3, v, 1);
        WT8p[idx] = v;
    }
    for (int idx = t0; idx < 2048 * 512; idx += stride) {
        const int n = idx >> 9, k = idx & 511;
        Wxb[idx] = f2b(Wih[n * 2 * H + k]);
        Wc[idx]  = f2b(Wih[n * 2 * H + H + k]);
    }
    for (int idx = t0; idx < 512 * 512; idx += stride)   Uab[idx]   = f2b(Ua[idx]);
    for (int idx = t0; idx < V * 512; idx += stride)     Woutb[idx] = f2b(Wout[idx]);
    for (int idx = t0; idx < BB * SS * H; idx += stride) encb[idx]  = f2b(enc[idx]);
    for (int j = t0; j < 2560; j += stride)
        bbig[j] = (j < H) ? ba[j] : bih[j - H] + bhh[j - H];
}

__global__ __launch_bounds__(256)
void gather_x(const float* __restrict__ emb, const int* __restrict__ tgt,
              unsigned short* __restrict__ xall)
{
    const int stride = gridDim.x * blockDim.x;
    for (int idx = blockIdx.x * blockDim.x + threadIdx.x; idx < TT * BB * H; idx += stride) {
        const int k = idx & 511;
        const int row = idx >> 9;
        const int t = row >> 7, b = row & 127;
        const int tok = (t == 0) ? 0 : tgt[b * TT + t - 1];
        xall[idx] = f2b(emb[(size_t)tok * H + k]);
    }
}

// ---------------------------------------------------------------------------
// bf16 MFMA NT-GEMM, K=512. OUT_MODE: 0=f32 (+PERMUTE r=t*B+b -> b*T+t),
// 1=bf16, 2=fp8. Used for keysb, encW8, xgates, logits.
// ---------------------------------------------------------------------------
template<int OUT_MODE, int PERMUTE>
__global__ __launch_bounds__(256, 2)
void gemm_mfma(const unsigned short* __restrict__ A,
               const unsigned short* __restrict__ B,
               const float* __restrict__ bias,
               float* __restrict__ Cf, unsigned short* __restrict__ Cb,
               unsigned char* __restrict__ C8,
               int M, int N)
{
    __shared__ unsigned short As[128][72];
    __shared__ unsigned short Bs[128][72];
    const int tid = threadIdx.x;
    const int m0 = blockIdx.y * 128, n0 = blockIdx.x * 128;
    const int lane = tid & 63, wv = tid >> 6;
    const int qm = (wv >> 1) * 64, qn = (wv & 1) * 64;
    const int fr = lane & 15, fg = lane >> 4;
    f32x4 acc[4][4];
#pragma unroll
    for (int i = 0; i < 4; ++i)
#pragma unroll
        for (int j = 0; j < 4; ++j) acc[i][j] = (f32x4){0.f, 0.f, 0.f, 0.f};

    const int srow = tid >> 3, sc = (tid & 7) * 8;
    for (int k0 = 0; k0 < H; k0 += 64) {
#pragma unroll
        for (int u = 0; u < 4; ++u) {
            const int row = srow + u * 32;
            *(uint4*)&As[row][sc] = *(const uint4*)&A[(size_t)(m0 + row) * H + k0 + sc];
            int nr = n0 + row; if (nr > N - 1) nr = N - 1;
            *(uint4*)&Bs[row][sc] = *(const uint4*)&B[(size_t)nr * H + k0 + sc];
        }
        __syncthreads();
#pragma unroll
        for (int ks = 0; ks < 2; ++ks) {
            const int kk = ks * 32 + fg * 8;
            bf16x8 av[4], bv[4];
#pragma unroll
            for (int i = 0; i < 4; ++i) {
                av[i] = *(const bf16x8*)&As[qm + i * 16 + fr][kk];
                bv[i] = *(const bf16x8*)&Bs[qn + i * 16 + fr][kk];
            }
#pragma unroll
            for (int i = 0; i < 4; ++i)
#pragma unroll
                for (int j = 0; j < 4; ++j)
                    acc[i][j] = __builtin_amdgcn_mfma_f32_16x16x32_bf16(av[i], bv[j], acc[i][j], 0, 0, 0);
        }
        __syncthreads();
    }
#pragma unroll
    for (int i = 0; i < 4; ++i) {
        const int r0 = m0 + qm + i * 16 + fg * 4;
#pragma unroll
        for (int j = 0; j < 4; ++j) {
            const int col = n0 + qn + j * 16 + fr;
            if (col < N) {
                const float bi = bias ? bias[col] : 0.f;
#pragma unroll
                for (int v = 0; v < 4; ++v) {
                    const int r = r0 + v;
                    const float val = acc[i][j][v] + bi;
                    if (OUT_MODE == 1) Cb[(size_t)r * N + col] = f2b(val);
                    else if (OUT_MODE == 2) C8[(size_t)r * N + col] = f2fp8(val);
                    else {
                        const size_t orow = PERMUTE ? ((size_t)(r & (BB - 1)) * TT + (r >> 7))
                                                    : (size_t)r;
                        Cf[orow * (size_t)N + col] = val;
                    }
                }
            }
        }
    }
}

struct PParams {
    const float* h0;
    const float* c0;
    const unsigned short* keysb;   // [B*S][512] bf16 (plain cached)
    const unsigned char* encW8;    // [B*S][2048] fp8 (plain cached)
    const float* Va;
    const float* bv;
    const float* bbig;             // [2560]
    const unsigned* WT8p;          // [128][2560] u32 fp8x4 (L2-resident)
    const unsigned short* xgates;  // [T*B][2048] bf16 (plain cached)
    unsigned short* hallb;         // [T*B][512] bf16 (next dispatch)
    float* attn;
    float* out_h;
    float* out_c;
};

// ---------------------------------------------------------------------------
// FULLY-LOCAL persistent recurrence: 128 blocks x 512 threads, block = one
// batch, ZERO cross-block communication (the h->Y GEMM is batch-local; the
// weight-amortization that previously forced block groups is replaced by
// fp8 weights small enough to be L2-resident per XCD). No flags, no hops,
// no placement assumptions -- the 2-hop x ~7us L3 sync cost (rounds 4-14,
// five protocol variants, all ~20+us/step) is structurally gone.
// Per step: GEMV Y[2560]=h.W^T (fp8 dequant + f32x2 FMA) -> scores/softmax
// -> gates = encW8-sum + Y[512:] + xgates -> LSTM (h,c in LDS, f32).
// ---------------------------------------------------------------------------
__global__ __launch_bounds__(512, 1)
void persist(PParams p)
{
    __shared__ float h_s[512];
    __shared__ float cs[512];
    __shared__ float va_s[512];
    __shared__ float ybuf[2560];
    __shared__ float part[SS][8];
    __shared__ float wbuf[SS];
    __shared__ float gbuf[2048];

    const int tid = threadIdx.x;
    const int gb  = blockIdx.x;          // batch

    h_s[tid]  = p.h0[(size_t)gb * H + tid];
    cs[tid]   = p.c0[(size_t)gb * H + tid];
    va_s[tid] = p.Va[tid];
    __syncthreads();

    for (int t = 0; t < TT; ++t) {
        // ---------------- GEMV: ybuf = h . W^T + bbig ----------------
        {
            f32x2 ac0 = {0.f, 0.f}, ac1 = {0.f, 0.f}, ac2 = {0.f, 0.f},
                  ac3 = {0.f, 0.f}, ac4 = {0.f, 0.f};
#pragma unroll 2
            for (int k4 = 0; k4 < 128; ++k4) {
                const f32x4 h4 = *(const f32x4*)&h_s[k4 * 4];
                const f32x2 a01 = {h4[0], h4[1]};
                const f32x2 a23 = {h4[2], h4[3]};
                const unsigned* wk = p.WT8p + (size_t)k4 * 2560 + tid;
                const unsigned w0 = wk[0];
                const unsigned w1 = wk[512];
                const unsigned w2 = wk[1024];
                const unsigned w3 = wk[1536];
                const unsigned w4 = wk[2048];
                ac0 += a01 * __builtin_amdgcn_cvt_pk_f32_fp8(w0, 0);
                ac0 += a23 * __builtin_amdgcn_cvt_pk_f32_fp8(w0, 1);
                ac1 += a01 * __builtin_amdgcn_cvt_pk_f32_fp8(w1, 0);
                ac1 += a23 * __builtin_amdgcn_cvt_pk_f32_fp8(w1, 1);
                ac2 += a01 * __builtin_amdgcn_cvt_pk_f32_fp8(w2, 0);
                ac2 += a23 * __builtin_amdgcn_cvt_pk_f32_fp8(w2, 1);
                ac3 += a01 * __builtin_amdgcn_cvt_pk_f32_fp8(w3, 0);
                ac3 += a23 * __builtin_amdgcn_cvt_pk_f32_fp8(w3, 1);
                ac4 += a01 * __builtin_amdgcn_cvt_pk_f32_fp8(w4, 0);
                ac4 += a23 * __builtin_amdgcn_cvt_pk_f32_fp8(w4, 1);
            }
            ybuf[tid]        = ac0[0] + ac0[1] + p.bbig[tid];
            ybuf[512 + tid]  = ac1[0] + ac1[1] + p.bbig[512 + tid];
            ybuf[1024 + tid] = ac2[0] + ac2[1] + p.bbig[1024 + tid];
            ybuf[1536 + tid] = ac3[0] + ac3[1] + p.bbig[1536 + tid];
            ybuf[2048 + tid] = ac4[0] + ac4[1] + p.bbig[2048 + tid];
        }
        __syncthreads();

        // ---------------- scores + softmax ----------------
        {
            const int s = tid >> 3, q = tid & 7;     // 64 chunks of 64
            const unsigned short* kp = p.keysb + ((size_t)gb * SS + s) * H + q * 64;
            const float* qp = ybuf + q * 64;
            const float* vp = va_s + q * 64;
            float a2 = 0.f, a2b = 0.f;
#pragma unroll
            for (int i8 = 0; i8 < 8; ++i8) {
                bf16x8 kv = *(const bf16x8*)&kp[i8 * 8];
#pragma unroll
                for (int u = 0; u < 8; u += 2) {
                    const int i = i8 * 8 + u;
                    a2  += ftanh(qp[i]     + b2f((unsigned short)kv[u]))     * vp[i];
                    a2b += ftanh(qp[i + 1] + b2f((unsigned short)kv[u + 1])) * vp[i + 1];
                }
            }
            part[s][q] = a2 + a2b;
        }
        __syncthreads();
        if (tid < 64) {
            float sc = part[tid][0] + part[tid][1] + part[tid][2] + part[tid][3]
                     + part[tid][4] + part[tid][5] + part[tid][6] + part[tid][7]
                     + p.bv[0];
            float m = sc;
            for (int o = 32; o; o >>= 1) m = fmaxf(m, __shfl_xor(m, o));
            const float e = __expf(sc - m);
            float ss = e;
            for (int o = 32; o; o >>= 1) ss += __shfl_xor(ss, o);
            const float w = e / ss;
            wbuf[tid] = w;
            p.attn[((size_t)gb * TT + t) * SS + tid] = w;
        }
        __syncthreads();

        // ---------------- gates = encW8-sum + Y[512:] + xgates ----------------
        {
            float gc0 = 0.f, gc1 = 0.f, gc2 = 0.f, gc3 = 0.f;
            const unsigned char* ew = p.encW8 + (size_t)gb * SS * 2048 + tid * 4;
#pragma unroll 8
            for (int s2 = 0; s2 < SS; ++s2) {
                const float w2 = wbuf[s2];
                const unsigned u = *(const unsigned*)(ew + (size_t)s2 * 2048);
                const f32x2 e01 = __builtin_amdgcn_cvt_pk_f32_fp8(u, 0);
                const f32x2 e23 = __builtin_amdgcn_cvt_pk_f32_fp8(u, 1);
                gc0 += w2 * e01[0]; gc1 += w2 * e01[1];
                gc2 += w2 * e23[0]; gc3 += w2 * e23[1];
            }
            const uint2 xu = *(const uint2*)&p.xgates[((size_t)t * BB + gb) * 2048 + tid * 4];
            gbuf[tid * 4 + 0] = gc0 + ybuf[512 + tid * 4 + 0] + b2f((unsigned short)(xu.x & 0xffffu));
            gbuf[tid * 4 + 1] = gc1 + ybuf[512 + tid * 4 + 1] + b2f((unsigned short)(xu.x >> 16));
            gbuf[tid * 4 + 2] = gc2 + ybuf[512 + tid * 4 + 2] + b2f((unsigned short)(xu.y & 0xffffu));
            gbuf[tid * 4 + 3] = gc3 + ybuf[512 + tid * 4 + 3] + b2f((unsigned short)(xu.y >> 16));
        }
        __syncthreads();

        // ---------------- LSTM (cell tid) ----------------
        {
            const float ig  = gbuf[tid];
            const float fgt = gbuf[512 + tid];
            const float gg  = gbuf[1024 + tid];
            const float og  = gbuf[1536 + tid];
            const float co  = cs[tid];
            const float cn = fsig(fgt) * co + fsig(ig) * ftanh(gg);
            const float hn = fsig(og) * ftanh(cn);
            cs[tid] = cn;
            h_s[tid] = hn;
            p.hallb[((size_t)t * BB + gb) * H + tid] = f2b(hn);
            if (t == TT - 1) {
                p.out_h[(size_t)gb * H + tid] = hn;
                p.out_c[(size_t)gb * H + tid] = cn;
            }
        }
        __syncthreads();
    }
}

// ---------------------------------------------------------------------------
// In-place log-softmax over each row of 5000 logits.
// ---------------------------------------------------------------------------
__global__ __launch_bounds__(256)
void logsoftmax_rows(float* __restrict__ P)
{
    __shared__ float red[256];
    float* p = P + (size_t)blockIdx.x * V;
    const int tid = threadIdx.x;
    float m = -1e30f;
    for (int i = tid; i < V; i += 256) m = fmaxf(m, p[i]);
    red[tid] = m; __syncthreads();
    for (int sft = 128; sft; sft >>= 1) {
        if (tid < sft) red[tid] = fmaxf(red[tid], red[tid + sft]);
        __syncthreads();
    }
    m = red[0]; __syncthreads();
    float ssum = 0.f;
    for (int i = tid; i < V; i += 256) ssum += __expf(p[i] - m);
    red[tid] = ssum; __syncthreads();
    for (int sft = 128; sft; sft >>= 1) {
        if (tid < sft) red[tid] += red[tid + sft];
        __syncthreads();
    }
    const float lse = m + __logf(red[0]);
    for (int i = tid; i < V; i += 256) p[i] -= lse;
}

// ---------------------------------------------------------------------------
extern "C" void kernel_launch(void* const* d_in, const int* in_sizes, int n_in,
                              void* d_out, int out_size, void* d_ws, size_t ws_size,
                              hipStream_t stream)
{
    (void)in_sizes; (void)n_in; (void)out_size; (void)ws_size;
    const float* enc  = (const float*)d_in[0];
    const float* h0   = (const float*)d_in[1];
    const float* c0   = (const float*)d_in[2];
    const int*   tgt  = (const int*)  d_in[3];
    const float* emb  = (const float*)d_in[4];
    const float* Wa   = (const float*)d_in[5];
    const float* ba   = (const float*)d_in[6];
    const float* Ua   = (const float*)d_in[7];
    const float* bu   = (const float*)d_in[8];
    const float* Va   = (const float*)d_in[9];
    const float* bv   = (const float*)d_in[10];
    const float* Wih  = (const float*)d_in[11];
    const float* Whh  = (const float*)d_in[12];
    const float* bih  = (const float*)d_in[13];
    const float* bhh  = (const float*)d_in[14];
    const float* Wout = (const float*)d_in[15];
    const float* bout = (const float*)d_in[16];

    float* ws = (float*)d_ws;
    float* bbig = ws;                                      // 2,560 f32
    unsigned* WT8p = (unsigned*)(bbig + 2560);             // 327,680 u32
    unsigned short* Wxb   = (unsigned short*)(WT8p + 327680);  // 1,048,576 u16
    unsigned short* Wc    = Wxb + 1048576;                 // 1,048,576
    unsigned short* Uab   = Wc + 1048576;                  // 262,144
    unsigned short* Woutb = Uab + 262144;                  // 2,560,000
    unsigned short* encb  = Woutb + 2560000;               // 4,194,304
    unsigned short* keysb = encb + 4194304;                // 4,194,304
    unsigned short* xall  = keysb + 4194304;               // 3,407,872
    unsigned short* xgates= xall + 3407872;                // 13,631,488
    unsigned short* hallb = xgates + 13631488;             // 3,407,872
    unsigned char*  encW8 = (unsigned char*)(hallb + 3407872); // 16,777,216 u8

    float* out    = (float*)d_out;
    float* out_h  = out + (size_t)BB * TT * V;
    float* out_c  = out_h + BB * H;
    float* out_at = out_c + BB * H;

    prep_w<<<dim3(2048), dim3(256), 0, stream>>>(
        Wa, Whh, Wih, ba, bih, bhh, Ua, Wout, enc,
        WT8p, Wxb, Wc, Uab, Woutb, encb, bbig);
    gather_x<<<dim3(512), dim3(256), 0, stream>>>(emb, tgt, xall);

    // keys_proj = enc @ Ua^T + bu -> bf16 [8192,512]
    gemm_mfma<1, 0><<<dim3(4, 64), dim3(256), 0, stream>>>(
        encb, Uab, bu, nullptr, keysb, nullptr, BB * SS, H);
    // encW8 = enc @ Wc^T -> fp8 [8192,2048]
    gemm_mfma<2, 0><<<dim3(16, 64), dim3(256), 0, stream>>>(
        encb, Wc, nullptr, nullptr, nullptr, encW8, BB * SS, 2048);
    // xgates = x @ Wx^T -> bf16 [6656,2048]  (teacher-forced x-part, hoisted)
    gemm_mfma<1, 0><<<dim3(16, 52), dim3(256), 0, stream>>>(
        xall, Wxb, nullptr, nullptr, xgates, nullptr, TT * BB, 2048);

    PParams pp;
    pp.h0 = h0; pp.c0 = c0; pp.keysb = keysb; pp.encW8 = encW8;
    pp.Va = Va; pp.bv = bv; pp.bbig = bbig;
    pp.WT8p = WT8p; pp.xgates = xgates;
    pp.hallb = hallb;
    pp.attn = out_at; pp.out_h = out_h; pp.out_c = out_c;
    persist<<<dim3(BB), dim3(512), 0, stream>>>(pp);

    // logits: hallb[6656,512] @ Woutb^T + bout -> out[b,t,:], then log-softmax
    gemm_mfma<0, 1><<<dim3(40, 52), dim3(256), 0, stream>>>(
        hallb, Woutb, bout, out, nullptr, nullptr, TT * BB, V);
    logsoftmax_rows<<<dim3(BB * TT), dim3(256), 0, stream>>>(out);
}

// Round 16
// 2600.649 us; speedup vs baseline: 1.0579x; 1.0579x over previous
//
#include <hip/hip_runtime.h>
#include <math.h>

#define H 512
#define V 5000
#define BB 128
#define SS 64
#define TT 52

typedef __attribute__((ext_vector_type(8))) short bf16x8;
typedef __attribute__((ext_vector_type(4))) float f32x4;
typedef __attribute__((ext_vector_type(2))) float f32x2;

__device__ __forceinline__ unsigned short f2b(float f) {
    unsigned u = __float_as_uint(f);
    return (unsigned short)((u + 0x7fffu + ((u >> 16) & 1u)) >> 16);
}
__device__ __forceinline__ float b2f(unsigned short u) {
    return __uint_as_float((unsigned)u << 16);
}
__device__ __forceinline__ float ftanh(float x) {
    return 1.f - 2.f / (1.f + __expf(2.f * x));
}
__device__ __forceinline__ float fsig(float x) {
    return 1.f / (1.f + __expf(-x));
}
__device__ __forceinline__ unsigned char f2fp8(float f) {
    return (unsigned char)__builtin_amdgcn_cvt_pk_fp8_f32(f, f, 0, 0);
}

// ---------------------------------------------------------------------------
// prep: WT8p [128][2560] u32 = fp8-packed TRANSPOSED recurrent weights
// (W = [Wa ; W_hh]; WT8p[k4][j] packs W[j][4k4..4k4+3]; 1.31MB -> L2-resident
// per XCD). Wxb/Wc bf16 for the hoisted GEMMs, bbig, bf16 Ua/Wout/enc.
// ---------------------------------------------------------------------------
__global__ __launch_bounds__(256)
void prep_w(const float* __restrict__ Wa, const float* __restrict__ Whh,
            const float* __restrict__ Wih,
            const float* __restrict__ ba, const float* __restrict__ bih,
            const float* __restrict__ bhh,
            const float* __restrict__ Ua, const float* __restrict__ Wout,
            const float* __restrict__ enc,
            unsigned* __restrict__ WT8p, unsigned short* __restrict__ Wxb,
            unsigned short* __restrict__ Wc,
            unsigned short* __restrict__ Uab, unsigned short* __restrict__ Woutb,
            unsigned short* __restrict__ encb, float* __restrict__ bbig)
{
    const int stride = gridDim.x * blockDim.x;
    const int t0 = blockIdx.x * blockDim.x + threadIdx.x;
    for (int idx = t0; idx < 128 * 2560; idx += stride) {
        const int k4 = idx / 2560;
        const int j  = idx - k4 * 2560;
        const int k  = k4 * 4;
        float w0, w1, w2, w3;
        if (j < H) {
            w0 = Wa[j * H + k];     w1 = Wa[j * H + k + 1];
            w2 = Wa[j * H + k + 2]; w3 = Wa[j * H + k + 3];
        } else {
            const int n = j - H;
            w0 = Whh[n * H + k];     w1 = Whh[n * H + k + 1];
            w2 = Whh[n * H + k + 2]; w3 = Whh[n * H + k + 3];
        }
        unsigned v = __builtin_amdgcn_cvt_pk_fp8_f32(w0, w1, 0u, 0);
        v = __builtin_amdgcn_cvt_pk_fp8_f32(w2, w3, v, 1);
        WT8p[idx] = v;
    }
    for (int idx = t0; idx < 2048 * 512; idx += stride) {
        const int n = idx >> 9, k = idx & 511;
        Wxb[idx] = f2b(Wih[n * 2 * H + k]);
        Wc[idx]  = f2b(Wih[n * 2 * H + H + k]);
    }
    for (int idx = t0; idx < 512 * 512; idx += stride)   Uab[idx]   = f2b(Ua[idx]);
    for (int idx = t0; idx < V * 512; idx += stride)     Woutb[idx] = f2b(Wout[idx]);
    for (int idx = t0; idx < BB * SS * H; idx += stride) encb[idx]  = f2b(enc[idx]);
    for (int j = t0; j < 2560; j += stride)
        bbig[j] = (j < H) ? ba[j] : bih[j - H] + bhh[j - H];
}

__global__ __launch_bounds__(256)
void gather_x(const float* __restrict__ emb, const int* __restrict__ tgt,
              unsigned short* __restrict__ xall)
{
    const int stride = gridDim.x * blockDim.x;
    for (int idx = blockIdx.x * blockDim.x + threadIdx.x; idx < TT * BB * H; idx += stride) {
        const int k = idx & 511;
        const int row = idx >> 9;
        const int t = row >> 7, b = row & 127;
        const int tok = (t == 0) ? 0 : tgt[b * TT + t - 1];
        xall[idx] = f2b(emb[(size_t)tok * H + k]);
    }
}

// ---------------------------------------------------------------------------
// bf16 MFMA NT-GEMM, K=512. OUT_MODE: 0=f32 (+PERMUTE r=t*B+b -> b*T+t),
// 1=bf16, 2=fp8. Used for keys8, encW8, xgates, logits.
// ---------------------------------------------------------------------------
template<int OUT_MODE, int PERMUTE>
__global__ __launch_bounds__(256, 2)
void gemm_mfma(const unsigned short* __restrict__ A,
               const unsigned short* __restrict__ B,
               const float* __restrict__ bias,
               float* __restrict__ Cf, unsigned short* __restrict__ Cb,
               unsigned char* __restrict__ C8,
               int M, int N)
{
    __shared__ unsigned short As[128][72];
    __shared__ unsigned short Bs[128][72];
    const int tid = threadIdx.x;
    const int m0 = blockIdx.y * 128, n0 = blockIdx.x * 128;
    const int lane = tid & 63, wv = tid >> 6;
    const int qm = (wv >> 1) * 64, qn = (wv & 1) * 64;
    const int fr = lane & 15, fg = lane >> 4;
    f32x4 acc[4][4];
#pragma unroll
    for (int i = 0; i < 4; ++i)
#pragma unroll
        for (int j = 0; j < 4; ++j) acc[i][j] = (f32x4){0.f, 0.f, 0.f, 0.f};

    const int srow = tid >> 3, sc = (tid & 7) * 8;
    for (int k0 = 0; k0 < H; k0 += 64) {
#pragma unroll
        for (int u = 0; u < 4; ++u) {
            const int row = srow + u * 32;
            *(uint4*)&As[row][sc] = *(const uint4*)&A[(size_t)(m0 + row) * H + k0 + sc];
            int nr = n0 + row; if (nr > N - 1) nr = N - 1;
            *(uint4*)&Bs[row][sc] = *(const uint4*)&B[(size_t)nr * H + k0 + sc];
        }
        __syncthreads();
#pragma unroll
        for (int ks = 0; ks < 2; ++ks) {
            const int kk = ks * 32 + fg * 8;
            bf16x8 av[4], bv[4];
#pragma unroll
            for (int i = 0; i < 4; ++i) {
                av[i] = *(const bf16x8*)&As[qm + i * 16 + fr][kk];
                bv[i] = *(const bf16x8*)&Bs[qn + i * 16 + fr][kk];
            }
#pragma unroll
            for (int i = 0; i < 4; ++i)
#pragma unroll
                for (int j = 0; j < 4; ++j)
                    acc[i][j] = __builtin_amdgcn_mfma_f32_16x16x32_bf16(av[i], bv[j], acc[i][j], 0, 0, 0);
        }
        __syncthreads();
    }
#pragma unroll
    for (int i = 0; i < 4; ++i) {
        const int r0 = m0 + qm + i * 16 + fg * 4;
#pragma unroll
        for (int j = 0; j < 4; ++j) {
            const int col = n0 + qn + j * 16 + fr;
            if (col < N) {
                const float bi = bias ? bias[col] : 0.f;
#pragma unroll
                for (int v = 0; v < 4; ++v) {
                    const int r = r0 + v;
                    const float val = acc[i][j][v] + bi;
                    if (OUT_MODE == 1) Cb[(size_t)r * N + col] = f2b(val);
                    else if (OUT_MODE == 2) C8[(size_t)r * N + col] = f2fp8(val);
                    else {
                        const size_t orow = PERMUTE ? ((size_t)(r & (BB - 1)) * TT + (r >> 7))
                                                    : (size_t)r;
                        Cf[orow * (size_t)N + col] = val;
                    }
                }
            }
        }
    }
}

struct PParams {
    const float* h0;
    const float* c0;
    const unsigned char* keys8;    // [B*S][512] fp8  (L2-resident slice)
    const unsigned char* encW8;    // [B*S][2048] fp8 (L2-resident slice)
    const float* Va;
    const float* bv;
    const float* bbig;             // [2560]
    const unsigned* WT8p;          // [128][2560] u32 fp8x4 (L2-resident)
    const unsigned short* xgates;  // [T*B][2048] bf16 (stream)
    unsigned short* hallb;         // [T*B][512] bf16 (next dispatch)
    float* attn;
    float* out_h;
    float* out_c;
};

// ---------------------------------------------------------------------------
// FULLY-LOCAL persistent recurrence v2: 128 blocks x 1024 threads (16
// waves/CU for latency hiding), block = one batch, zero cross-block comm.
// L2 working set per XCD: WT8p 1.31MB + encW8 2.0MB + keys8 0.5MB = 3.8MB
// < 4MB (r15's 4.3MB thrashed -> 650MB refetch, 49us/step stall-bound).
// Per step: GEMV Y[2560]=h.W^T (fp8 dequant + pk_fma, 2.5 out/thread) ->
// scores/softmax -> gates = encW8-sum + Y[512:] + xgates -> LSTM (f32 LDS).
// ---------------------------------------------------------------------------
__global__ __launch_bounds__(1024, 1)
void persist(PParams p)
{
    __shared__ float h_s[512];
    __shared__ float cs[512];
    __shared__ float va_s[512];
    __shared__ float ybuf[2560];
    __shared__ float part[SS][16];
    __shared__ float wbuf[SS];
    __shared__ float gbuf[2048];

    const int tid = threadIdx.x;
    const int gb  = blockIdx.x;          // batch

    if (tid < 512) {
        h_s[tid]  = p.h0[(size_t)gb * H + tid];
        cs[tid]   = p.c0[(size_t)gb * H + tid];
        va_s[tid] = p.Va[tid];
    }
    __syncthreads();

    for (int t = 0; t < TT; ++t) {
        // ---------------- GEMV: ybuf = h . W^T + bbig ----------------
        {
            f32x2 ac0 = {0.f, 0.f}, ac1 = {0.f, 0.f}, ac2 = {0.f, 0.f};
            const bool third = (tid < 512);
#pragma unroll 4
            for (int k4 = 0; k4 < 128; ++k4) {
                const f32x4 h4 = *(const f32x4*)&h_s[k4 * 4];
                const f32x2 a01 = {h4[0], h4[1]};
                const f32x2 a23 = {h4[2], h4[3]};
                const unsigned* wk = p.WT8p + (size_t)k4 * 2560 + tid;
                const unsigned w0 = wk[0];
                const unsigned w1 = wk[1024];
                ac0 += a01 * __builtin_amdgcn_cvt_pk_f32_fp8(w0, 0);
                ac0 += a23 * __builtin_amdgcn_cvt_pk_f32_fp8(w0, 1);
                ac1 += a01 * __builtin_amdgcn_cvt_pk_f32_fp8(w1, 0);
                ac1 += a23 * __builtin_amdgcn_cvt_pk_f32_fp8(w1, 1);
                if (third) {
                    const unsigned w2 = wk[2048];
                    ac2 += a01 * __builtin_amdgcn_cvt_pk_f32_fp8(w2, 0);
                    ac2 += a23 * __builtin_amdgcn_cvt_pk_f32_fp8(w2, 1);
                }
            }
            ybuf[tid]        = ac0[0] + ac0[1] + p.bbig[tid];
            ybuf[1024 + tid] = ac1[0] + ac1[1] + p.bbig[1024 + tid];
            if (third)
                ybuf[2048 + tid] = ac2[0] + ac2[1] + p.bbig[2048 + tid];
        }
        __syncthreads();

        // ---------------- scores + softmax ----------------
        {
            const int s = tid >> 4, q = tid & 15;    // 64 s x 16 chunks of 32
            const unsigned char* kp = p.keys8 + ((size_t)gb * SS + s) * H + q * 32;
            const float* qp = ybuf + q * 32;
            const float* vp = va_s + q * 32;
            float a2 = 0.f, a2b = 0.f;
#pragma unroll
            for (int i4 = 0; i4 < 8; ++i4) {
                const unsigned u = *(const unsigned*)(kp + i4 * 4);
                const f32x2 k01 = __builtin_amdgcn_cvt_pk_f32_fp8(u, 0);
                const f32x2 k23 = __builtin_amdgcn_cvt_pk_f32_fp8(u, 1);
                const int i = i4 * 4;
                a2  += ftanh(qp[i]     + k01[0]) * vp[i];
                a2b += ftanh(qp[i + 1] + k01[1]) * vp[i + 1];
                a2  += ftanh(qp[i + 2] + k23[0]) * vp[i + 2];
                a2b += ftanh(qp[i + 3] + k23[1]) * vp[i + 3];
            }
            part[s][q] = a2 + a2b;
        }
        __syncthreads();
        if (tid < 64) {
            float sc = p.bv[0];
#pragma unroll
            for (int q = 0; q < 16; ++q) sc += part[tid][q];
            float m = sc;
            for (int o = 32; o; o >>= 1) m = fmaxf(m, __shfl_xor(m, o));
            const float e = __expf(sc - m);
            float ss = e;
            for (int o = 32; o; o >>= 1) ss += __shfl_xor(ss, o);
            const float w = e / ss;
            wbuf[tid] = w;
            p.attn[((size_t)gb * TT + t) * SS + tid] = w;
        }
        __syncthreads();

        // -------- gates = encW8-sum + Y[512:] + xgates (2 per thread) -------
        {
            float gc0 = 0.f, gc1 = 0.f;
            const unsigned char* ew = p.encW8 + (size_t)gb * SS * 2048 + tid * 2;
#pragma unroll 8
            for (int s2 = 0; s2 < SS; ++s2) {
                const float w2 = wbuf[s2];
                const unsigned short u =
                    *(const unsigned short*)(ew + (size_t)s2 * 2048);
                const f32x2 e01 = __builtin_amdgcn_cvt_pk_f32_fp8((unsigned)u, 0);
                gc0 += w2 * e01[0];
                gc1 += w2 * e01[1];
            }
            const unsigned xu =
                *(const unsigned*)&p.xgates[((size_t)t * BB + gb) * 2048 + tid * 2];
            gbuf[tid * 2 + 0] = gc0 + ybuf[512 + tid * 2 + 0] + b2f((unsigned short)(xu & 0xffffu));
            gbuf[tid * 2 + 1] = gc1 + ybuf[512 + tid * 2 + 1] + b2f((unsigned short)(xu >> 16));
        }
        __syncthreads();

        // ---------------- LSTM (cell = tid, tid < 512) ----------------
        if (tid < 512) {
            const float ig  = gbuf[tid];
            const float fgt = gbuf[512 + tid];
            const float gg  = gbuf[1024 + tid];
            const float og  = gbuf[1536 + tid];
            const float co  = cs[tid];
            const float cn = fsig(fgt) * co + fsig(ig) * ftanh(gg);
            const float hn = fsig(og) * ftanh(cn);
            cs[tid] = cn;
            h_s[tid] = hn;
            p.hallb[((size_t)t * BB + gb) * H + tid] = f2b(hn);
            if (t == TT - 1) {
                p.out_h[(size_t)gb * H + tid] = hn;
                p.out_c[(size_t)gb * H + tid] = cn;
            }
        }
        __syncthreads();
    }
}

// ---------------------------------------------------------------------------
// In-place log-softmax over each row of 5000 logits.
// ---------------------------------------------------------------------------
__global__ __launch_bounds__(256)
void logsoftmax_rows(float* __restrict__ P)
{
    __shared__ float red[256];
    float* p = P + (size_t)blockIdx.x * V;
    const int tid = threadIdx.x;
    float m = -1e30f;
    for (int i = tid; i < V; i += 256) m = fmaxf(m, p[i]);
    red[tid] = m; __syncthreads();
    for (int sft = 128; sft; sft >>= 1) {
        if (tid < sft) red[tid] = fmaxf(red[tid], red[tid + sft]);
        __syncthreads();
    }
    m = red[0]; __syncthreads();
    float ssum = 0.f;
    for (int i = tid; i < V; i += 256) ssum += __expf(p[i] - m);
    red[tid] = ssum; __syncthreads();
    for (int sft = 128; sft; sft >>= 1) {
        if (tid < sft) red[tid] += red[tid + sft];
        __syncthreads();
    }
    const float lse = m + __logf(red[0]);
    for (int i = tid; i < V; i += 256) p[i] -= lse;
}

// ---------------------------------------------------------------------------
extern "C" void kernel_launch(void* const* d_in, const int* in_sizes, int n_in,
                              void* d_out, int out_size, void* d_ws, size_t ws_size,
                              hipStream_t stream)
{
    (void)in_sizes; (void)n_in; (void)out_size; (void)ws_size;
    const float* enc  = (const float*)d_in[0];
    const float* h0   = (const float*)d_in[1];
    const float* c0   = (const float*)d_in[2];
    const int*   tgt  = (const int*)  d_in[3];
    const float* emb  = (const float*)d_in[4];
    const float* Wa   = (const float*)d_in[5];
    const float* ba   = (const float*)d_in[6];
    const float* Ua   = (const float*)d_in[7];
    const float* bu   = (const float*)d_in[8];
    const float* Va   = (const float*)d_in[9];
    const float* bv   = (const float*)d_in[10];
    const float* Wih  = (const float*)d_in[11];
    const float* Whh  = (const float*)d_in[12];
    const float* bih  = (const float*)d_in[13];
    const float* bhh  = (const float*)d_in[14];
    const float* Wout = (const float*)d_in[15];
    const float* bout = (const float*)d_in[16];

    float* ws = (float*)d_ws;
    float* bbig = ws;                                      // 2,560 f32
    unsigned* WT8p = (unsigned*)(bbig + 2560);             // 327,680 u32
    unsigned short* Wxb   = (unsigned short*)(WT8p + 327680);  // 1,048,576 u16
    unsigned short* Wc    = Wxb + 1048576;                 // 1,048,576
    unsigned short* Uab   = Wc + 1048576;                  // 262,144
    unsigned short* Woutb = Uab + 262144;                  // 2,560,000
    unsigned short* encb  = Woutb + 2560000;               // 4,194,304
    unsigned short* xall  = encb + 4194304;                // 3,407,872
    unsigned short* xgates= xall + 3407872;                // 13,631,488
    unsigned short* hallb = xgates + 13631488;             // 3,407,872
    unsigned char*  encW8 = (unsigned char*)(hallb + 3407872); // 16,777,216 u8
    unsigned char*  keys8 = encW8 + 16777216;              // 4,194,304 u8

    float* out    = (float*)d_out;
    float* out_h  = out + (size_t)BB * TT * V;
    float* out_c  = out_h + BB * H;
    float* out_at = out_c + BB * H;

    prep_w<<<dim3(2048), dim3(256), 0, stream>>>(
        Wa, Whh, Wih, ba, bih, bhh, Ua, Wout, enc,
        WT8p, Wxb, Wc, Uab, Woutb, encb, bbig);
    gather_x<<<dim3(512), dim3(256), 0, stream>>>(emb, tgt, xall);

    // keys8 = enc @ Ua^T + bu -> fp8 [8192,512]
    gemm_mfma<2, 0><<<dim3(4, 64), dim3(256), 0, stream>>>(
        encb, Uab, bu, nullptr, nullptr, keys8, BB * SS, H);
    // encW8 = enc @ Wc^T -> fp8 [8192,2048]
    gemm_mfma<2, 0><<<dim3(16, 64), dim3(256), 0, stream>>>(
        encb, Wc, nullptr, nullptr, nullptr, encW8, BB * SS, 2048);
    // xgates = x @ Wx^T -> bf16 [6656,2048]  (teacher-forced x-part, hoisted)
    gemm_mfma<1, 0><<<dim3(16, 52), dim3(256), 0, stream>>>(
        xall, Wxb, nullptr, nullptr, xgates, nullptr, TT * BB, 2048);

    PParams pp;
    pp.h0 = h0; pp.c0 = c0; pp.keys8 = keys8; pp.encW8 = encW8;
    pp.Va = Va; pp.bv = bv; pp.bbig = bbig;
    pp.WT8p = WT8p; pp.xgates = xgates;
    pp.hallb = hallb;
    pp.attn = out_at; pp.out_h = out_h; pp.out_c = out_c;
    persist<<<dim3(BB), dim3(1024), 0, stream>>>(pp);

    // logits: hallb[6656,512] @ Woutb^T + bout -> out[b,t,:], then log-softmax
    gemm_mfma<0, 1><<<dim3(40, 52), dim3(256), 0, stream>>>(
        hallb, Woutb, bout, out, nullptr, nullptr, TT * BB, V);
    logsoftmax_rows<<<dim3(BB * TT), dim3(256), 0, stream>>>(out);
}

// Round 17
// 2007.406 us; speedup vs baseline: 1.3705x; 1.2955x over previous
//
#include <hip/hip_runtime.h>
#include <math.h>

#define H 512
#define V 5000
#define BB 128
#define SS 64
#define TT 52

typedef __attribute__((ext_vector_type(8))) short bf16x8;
typedef __attribute__((ext_vector_type(4))) float f32x4;
typedef __attribute__((ext_vector_type(2))) float f32x2;

__device__ __forceinline__ unsigned short f2b(float f) {
    unsigned u = __float_as_uint(f);
    return (unsigned short)((u + 0x7fffu + ((u >> 16) & 1u)) >> 16);
}
__device__ __forceinline__ float b2f(unsigned short u) {
    return __uint_as_float((unsigned)u << 16);
}
__device__ __forceinline__ float ftanh(float x) {
    return 1.f - 2.f / (1.f + __expf(2.f * x));
}
__device__ __forceinline__ float fsig(float x) {
    return 1.f / (1.f + __expf(-x));
}
__device__ __forceinline__ unsigned char f2fp8(float f) {
    return (unsigned char)__builtin_amdgcn_cvt_pk_fp8_f32(f, f, 0, 0);
}

// ---------------------------------------------------------------------------
// prep: WT8p [128][2560] u32 = fp8-packed TRANSPOSED recurrent weights
// (W = [Wa ; W_hh]; WT8p[k4][j] packs W[j][4k4..4k4+3]).
// Wxb/Wc bf16 for the hoisted GEMMs, bbig, bf16 Ua/Wout/enc.
// ---------------------------------------------------------------------------
__global__ __launch_bounds__(256)
void prep_w(const float* __restrict__ Wa, const float* __restrict__ Whh,
            const float* __restrict__ Wih,
            const float* __restrict__ ba, const float* __restrict__ bih,
            const float* __restrict__ bhh,
            const float* __restrict__ Ua, const float* __restrict__ Wout,
            const float* __restrict__ enc,
            unsigned* __restrict__ WT8p, unsigned short* __restrict__ Wxb,
            unsigned short* __restrict__ Wc,
            unsigned short* __restrict__ Uab, unsigned short* __restrict__ Woutb,
            unsigned short* __restrict__ encb, float* __restrict__ bbig)
{
    const int stride = gridDim.x * blockDim.x;
    const int t0 = blockIdx.x * blockDim.x + threadIdx.x;
    for (int idx = t0; idx < 128 * 2560; idx += stride) {
        const int k4 = idx / 2560;
        const int j  = idx - k4 * 2560;
        const int k  = k4 * 4;
        float w0, w1, w2, w3;
        if (j < H) {
            w0 = Wa[j * H + k];     w1 = Wa[j * H + k + 1];
            w2 = Wa[j * H + k + 2]; w3 = Wa[j * H + k + 3];
        } else {
            const int n = j - H;
            w0 = Whh[n * H + k];     w1 = Whh[n * H + k + 1];
            w2 = Whh[n * H + k + 2]; w3 = Whh[n * H + k + 3];
        }
        unsigned v = __builtin_amdgcn_cvt_pk_fp8_f32(w0, w1, 0u, 0);
        v = __builtin_amdgcn_cvt_pk_fp8_f32(w2, w3, v, 1);
        WT8p[idx] = v;
    }
    for (int idx = t0; idx < 2048 * 512; idx += stride) {
        const int n = idx >> 9, k = idx & 511;
        Wxb[idx] = f2b(Wih[n * 2 * H + k]);
        Wc[idx]  = f2b(Wih[n * 2 * H + H + k]);
    }
    for (int idx = t0; idx < 512 * 512; idx += stride)   Uab[idx]   = f2b(Ua[idx]);
    for (int idx = t0; idx < V * 512; idx += stride)     Woutb[idx] = f2b(Wout[idx]);
    for (int idx = t0; idx < BB * SS * H; idx += stride) encb[idx]  = f2b(enc[idx]);
    for (int j = t0; j < 2560; j += stride)
        bbig[j] = (j < H) ? ba[j] : bih[j - H] + bhh[j - H];
}

__global__ __launch_bounds__(256)
void gather_x(const float* __restrict__ emb, const int* __restrict__ tgt,
              unsigned short* __restrict__ xall)
{
    const int stride = gridDim.x * blockDim.x;
    for (int idx = blockIdx.x * blockDim.x + threadIdx.x; idx < TT * BB * H; idx += stride) {
        const int k = idx & 511;
        const int row = idx >> 9;
        const int t = row >> 7, b = row & 127;
        const int tok = (t == 0) ? 0 : tgt[b * TT + t - 1];
        xall[idx] = f2b(emb[(size_t)tok * H + k]);
    }
}

// ---------------------------------------------------------------------------
// bf16 MFMA NT-GEMM, K=512. OUT_MODE: 0=f32 (+PERMUTE r=t*B+b -> b*T+t),
// 1=bf16, 2=fp8. Used for keys8, encW8, xgates, logits.
// ---------------------------------------------------------------------------
template<int OUT_MODE, int PERMUTE>
__global__ __launch_bounds__(256, 2)
void gemm_mfma(const unsigned short* __restrict__ A,
               const unsigned short* __restrict__ B,
               const float* __restrict__ bias,
               float* __restrict__ Cf, unsigned short* __restrict__ Cb,
               unsigned char* __restrict__ C8,
               int M, int N)
{
    __shared__ unsigned short As[128][72];
    __shared__ unsigned short Bs[128][72];
    const int tid = threadIdx.x;
    const int m0 = blockIdx.y * 128, n0 = blockIdx.x * 128;
    const int lane = tid & 63, wv = tid >> 6;
    const int qm = (wv >> 1) * 64, qn = (wv & 1) * 64;
    const int fr = lane & 15, fg = lane >> 4;
    f32x4 acc[4][4];
#pragma unroll
    for (int i = 0; i < 4; ++i)
#pragma unroll
        for (int j = 0; j < 4; ++j) acc[i][j] = (f32x4){0.f, 0.f, 0.f, 0.f};

    const int srow = tid >> 3, sc = (tid & 7) * 8;
    for (int k0 = 0; k0 < H; k0 += 64) {
#pragma unroll
        for (int u = 0; u < 4; ++u) {
            const int row = srow + u * 32;
            *(uint4*)&As[row][sc] = *(const uint4*)&A[(size_t)(m0 + row) * H + k0 + sc];
            int nr = n0 + row; if (nr > N - 1) nr = N - 1;
            *(uint4*)&Bs[row][sc] = *(const uint4*)&B[(size_t)nr * H + k0 + sc];
        }
        __syncthreads();
#pragma unroll
        for (int ks = 0; ks < 2; ++ks) {
            const int kk = ks * 32 + fg * 8;
            bf16x8 av[4], bv[4];
#pragma unroll
            for (int i = 0; i < 4; ++i) {
                av[i] = *(const bf16x8*)&As[qm + i * 16 + fr][kk];
                bv[i] = *(const bf16x8*)&Bs[qn + i * 16 + fr][kk];
            }
#pragma unroll
            for (int i = 0; i < 4; ++i)
#pragma unroll
                for (int j = 0; j < 4; ++j)
                    acc[i][j] = __builtin_amdgcn_mfma_f32_16x16x32_bf16(av[i], bv[j], acc[i][j], 0, 0, 0);
        }
        __syncthreads();
    }
#pragma unroll
    for (int i = 0; i < 4; ++i) {
        const int r0 = m0 + qm + i * 16 + fg * 4;
#pragma unroll
        for (int j = 0; j < 4; ++j) {
            const int col = n0 + qn + j * 16 + fr;
            if (col < N) {
                const float bi = bias ? bias[col] : 0.f;
#pragma unroll
                for (int v = 0; v < 4; ++v) {
                    const int r = r0 + v;
                    const float val = acc[i][j][v] + bi;
                    if (OUT_MODE == 1) Cb[(size_t)r * N + col] = f2b(val);
                    else if (OUT_MODE == 2) C8[(size_t)r * N + col] = f2fp8(val);
                    else {
                        const size_t orow = PERMUTE ? ((size_t)(r & (BB - 1)) * TT + (r >> 7))
                                                    : (size_t)r;
                        Cf[orow * (size_t)N + col] = val;
                    }
                }
            }
        }
    }
}

struct PParams {
    const float* h0;
    const float* c0;
    const unsigned char* keys8;    // [B*S][512] fp8
    const unsigned char* encW8;    // [B*S][2048] fp8
    const float* Va;
    const float* bv;
    const float* bbig;             // [2560]
    const unsigned* WT8p;          // [128][2560] u32 fp8x4
    const unsigned short* xgates;  // [T*B][2048] bf16
    unsigned short* hallb;         // [T*B][512] bf16
    float* attn;
    float* out_h;
    float* out_c;
};

// ---------------------------------------------------------------------------
// FULLY-LOCAL persistent recurrence v3: r16 + PHASE-STAGGERED weight sweep.
// r16 diagnosis: all 16 same-XCD blocks swept WT8p in the SAME order ->
// correlated miss storm (every block waits on every cold line: ~20K lines x
// 900cy / ~160 outstanding = ~46us/step, the measured wall time). Rotating
// each block's k4 start by slot*8 (sum order is commutative) makes each
// block first-touch only its own 1/16 of the matrix (~3us, hideable) and
// hit lines its peers just fetched.
// ---------------------------------------------------------------------------
__global__ __launch_bounds__(1024, 1)
void persist(PParams p)
{
    __shared__ float h_s[512];
    __shared__ float cs[512];
    __shared__ float va_s[512];
    __shared__ float ybuf[2560];
    __shared__ float part[SS][16];
    __shared__ float wbuf[SS];
    __shared__ float gbuf[2048];

    const int tid = threadIdx.x;
    const int gb  = blockIdx.x;          // batch
    const int ph  = (gb >> 3) & 15;      // same-XCD blocks (gb%8 alike) differ

    if (tid < 512) {
        h_s[tid]  = p.h0[(size_t)gb * H + tid];
        cs[tid]   = p.c0[(size_t)gb * H + tid];
        va_s[tid] = p.Va[tid];
    }
    const float bb0 = p.bbig[tid];
    const float bb1 = p.bbig[1024 + tid];
    const float bb2 = (tid < 512) ? p.bbig[2048 + tid] : 0.f;
    __syncthreads();

    for (int t = 0; t < TT; ++t) {
        // ------- GEMV: ybuf = h . W^T + bbig (phase-staggered k sweep) ------
        {
            f32x2 ac0 = {0.f, 0.f}, ac1 = {0.f, 0.f}, ac2 = {0.f, 0.f};
            const bool third = (tid < 512);
#pragma unroll
            for (int seg = 0; seg < 2; ++seg) {
                const int k4lo = seg ? 0 : ph * 8;
                const int k4hi = seg ? ph * 8 : 128;
#pragma unroll 4
                for (int k4 = k4lo; k4 < k4hi; ++k4) {
                    const f32x4 h4 = *(const f32x4*)&h_s[k4 * 4];
                    const f32x2 a01 = {h4[0], h4[1]};
                    const f32x2 a23 = {h4[2], h4[3]};
                    const unsigned* wk = p.WT8p + (size_t)k4 * 2560 + tid;
                    const unsigned w0 = wk[0];
                    const unsigned w1 = wk[1024];
                    ac0 += a01 * __builtin_amdgcn_cvt_pk_f32_fp8(w0, 0);
                    ac0 += a23 * __builtin_amdgcn_cvt_pk_f32_fp8(w0, 1);
                    ac1 += a01 * __builtin_amdgcn_cvt_pk_f32_fp8(w1, 0);
                    ac1 += a23 * __builtin_amdgcn_cvt_pk_f32_fp8(w1, 1);
                    if (third) {
                        const unsigned w2 = wk[2048];
                        ac2 += a01 * __builtin_amdgcn_cvt_pk_f32_fp8(w2, 0);
                        ac2 += a23 * __builtin_amdgcn_cvt_pk_f32_fp8(w2, 1);
                    }
                }
            }
            ybuf[tid]        = ac0[0] + ac0[1] + bb0;
            ybuf[1024 + tid] = ac1[0] + ac1[1] + bb1;
            if (third)
                ybuf[2048 + tid] = ac2[0] + ac2[1] + bb2;
        }
        __syncthreads();

        // ---------------- scores + softmax ----------------
        {
            const int s = tid >> 4, q = tid & 15;    // 64 s x 16 chunks of 32
            const unsigned char* kp = p.keys8 + ((size_t)gb * SS + s) * H + q * 32;
            const float* qp = ybuf + q * 32;
            const float* vp = va_s + q * 32;
            float a2 = 0.f, a2b = 0.f;
#pragma unroll
            for (int i4 = 0; i4 < 8; ++i4) {
                const unsigned u = *(const unsigned*)(kp + i4 * 4);
                const f32x2 k01 = __builtin_amdgcn_cvt_pk_f32_fp8(u, 0);
                const f32x2 k23 = __builtin_amdgcn_cvt_pk_f32_fp8(u, 1);
                const int i = i4 * 4;
                a2  += ftanh(qp[i]     + k01[0]) * vp[i];
                a2b += ftanh(qp[i + 1] + k01[1]) * vp[i + 1];
                a2  += ftanh(qp[i + 2] + k23[0]) * vp[i + 2];
                a2b += ftanh(qp[i + 3] + k23[1]) * vp[i + 3];
            }
            part[s][q] = a2 + a2b;
        }
        __syncthreads();
        if (tid < 64) {
            float sc = p.bv[0];
#pragma unroll
            for (int q = 0; q < 16; ++q) sc += part[tid][q];
            float m = sc;
            for (int o = 32; o; o >>= 1) m = fmaxf(m, __shfl_xor(m, o));
            const float e = __expf(sc - m);
            float ss = e;
            for (int o = 32; o; o >>= 1) ss += __shfl_xor(ss, o);
            const float w = e / ss;
            wbuf[tid] = w;
            p.attn[((size_t)gb * TT + t) * SS + tid] = w;
        }
        __syncthreads();

        // -------- gates = encW8-sum + Y[512:] + xgates (2 per thread) -------
        {
            float gc0 = 0.f, gc1 = 0.f;
            const unsigned char* ew = p.encW8 + (size_t)gb * SS * 2048 + tid * 2;
#pragma unroll 8
            for (int s2 = 0; s2 < SS; ++s2) {
                const float w2 = wbuf[s2];
                const unsigned short u =
                    *(const unsigned short*)(ew + (size_t)s2 * 2048);
                const f32x2 e01 = __builtin_amdgcn_cvt_pk_f32_fp8((unsigned)u, 0);
                gc0 += w2 * e01[0];
                gc1 += w2 * e01[1];
            }
            const unsigned xu =
                *(const unsigned*)&p.xgates[((size_t)t * BB + gb) * 2048 + tid * 2];
            gbuf[tid * 2 + 0] = gc0 + ybuf[512 + tid * 2 + 0] + b2f((unsigned short)(xu & 0xffffu));
            gbuf[tid * 2 + 1] = gc1 + ybuf[512 + tid * 2 + 1] + b2f((unsigned short)(xu >> 16));
        }
        __syncthreads();

        // ---------------- LSTM (cell = tid, tid < 512) ----------------
        if (tid < 512) {
            const float ig  = gbuf[tid];
            const float fgt = gbuf[512 + tid];
            const float gg  = gbuf[1024 + tid];
            const float og  = gbuf[1536 + tid];
            const float co  = cs[tid];
            const float cn = fsig(fgt) * co + fsig(ig) * ftanh(gg);
            const float hn = fsig(og) * ftanh(cn);
            cs[tid] = cn;
            h_s[tid] = hn;
            p.hallb[((size_t)t * BB + gb) * H + tid] = f2b(hn);
            if (t == TT - 1) {
                p.out_h[(size_t)gb * H + tid] = hn;
                p.out_c[(size_t)gb * H + tid] = cn;
            }
        }
        __syncthreads();
    }
}

// ---------------------------------------------------------------------------
// In-place log-softmax over each row of 5000 logits.
// ---------------------------------------------------------------------------
__global__ __launch_bounds__(256)
void logsoftmax_rows(float* __restrict__ P)
{
    __shared__ float red[256];
    float* p = P + (size_t)blockIdx.x * V;
    const int tid = threadIdx.x;
    float m = -1e30f;
    for (int i = tid; i < V; i += 256) m = fmaxf(m, p[i]);
    red[tid] = m; __syncthreads();
    for (int sft = 128; sft; sft >>= 1) {
        if (tid < sft) red[tid] = fmaxf(red[tid], red[tid + sft]);
        __syncthreads();
    }
    m = red[0]; __syncthreads();
    float ssum = 0.f;
    for (int i = tid; i < V; i += 256) ssum += __expf(p[i] - m);
    red[tid] = ssum; __syncthreads();
    for (int sft = 128; sft; sft >>= 1) {
        if (tid < sft) red[tid] += red[tid + sft];
        __syncthreads();
    }
    const float lse = m + __logf(red[0]);
    for (int i = tid; i < V; i += 256) p[i] -= lse;
}

// ---------------------------------------------------------------------------
extern "C" void kernel_launch(void* const* d_in, const int* in_sizes, int n_in,
                              void* d_out, int out_size, void* d_ws, size_t ws_size,
                              hipStream_t stream)
{
    (void)in_sizes; (void)n_in; (void)out_size; (void)ws_size;
    const float* enc  = (const float*)d_in[0];
    const float* h0   = (const float*)d_in[1];
    const float* c0   = (const float*)d_in[2];
    const int*   tgt  = (const int*)  d_in[3];
    const float* emb  = (const float*)d_in[4];
    const float* Wa   = (const float*)d_in[5];
    const float* ba   = (const float*)d_in[6];
    const float* Ua   = (const float*)d_in[7];
    const float* bu   = (const float*)d_in[8];
    const float* Va   = (const float*)d_in[9];
    const float* bv   = (const float*)d_in[10];
    const float* Wih  = (const float*)d_in[11];
    const float* Whh  = (const float*)d_in[12];
    const float* bih  = (const float*)d_in[13];
    const float* bhh  = (const float*)d_in[14];
    const float* Wout = (const float*)d_in[15];
    const float* bout = (const float*)d_in[16];

    float* ws = (float*)d_ws;
    float* bbig = ws;                                      // 2,560 f32
    unsigned* WT8p = (unsigned*)(bbig + 2560);             // 327,680 u32
    unsigned short* Wxb   = (unsigned short*)(WT8p + 327680);  // 1,048,576 u16
    unsigned short* Wc    = Wxb + 1048576;                 // 1,048,576
    unsigned short* Uab   = Wc + 1048576;                  // 262,144
    unsigned short* Woutb = Uab + 262144;                  // 2,560,000
    unsigned short* encb  = Woutb + 2560000;               // 4,194,304
    unsigned short* xall  = encb + 4194304;                // 3,407,872
    unsigned short* xgates= xall + 3407872;                // 13,631,488
    unsigned short* hallb = xgates + 13631488;             // 3,407,872
    unsigned char*  encW8 = (unsigned char*)(hallb + 3407872); // 16,777,216 u8
    unsigned char*  keys8 = encW8 + 16777216;              // 4,194,304 u8

    float* out    = (float*)d_out;
    float* out_h  = out + (size_t)BB * TT * V;
    float* out_c  = out_h + BB * H;
    float* out_at = out_c + BB * H;

    prep_w<<<dim3(2048), dim3(256), 0, stream>>>(
        Wa, Whh, Wih, ba, bih, bhh, Ua, Wout, enc,
        WT8p, Wxb, Wc, Uab, Woutb, encb, bbig);
    gather_x<<<dim3(512), dim3(256), 0, stream>>>(emb, tgt, xall);

    // keys8 = enc @ Ua^T + bu -> fp8 [8192,512]
    gemm_mfma<2, 0><<<dim3(4, 64), dim3(256), 0, stream>>>(
        encb, Uab, bu, nullptr, nullptr, keys8, BB * SS, H);
    // encW8 = enc @ Wc^T -> fp8 [8192,2048]
    gemm_mfma<2, 0><<<dim3(16, 64), dim3(256), 0, stream>>>(
        encb, Wc, nullptr, nullptr, nullptr, encW8, BB * SS, 2048);
    // xgates = x @ Wx^T -> bf16 [6656,2048]  (teacher-forced x-part, hoisted)
    gemm_mfma<1, 0><<<dim3(16, 52), dim3(256), 0, stream>>>(
        xall, Wxb, nullptr, nullptr, xgates, nullptr, TT * BB, 2048);

    PParams pp;
    pp.h0 = h0; pp.c0 = c0; pp.keys8 = keys8; pp.encW8 = encW8;
    pp.Va = Va; pp.bv = bv; pp.bbig = bbig;
    pp.WT8p = WT8p; pp.xgates = xgates;
    pp.hallb = hallb;
    pp.attn = out_at; pp.out_h = out_h; pp.out_c = out_c;
    persist<<<dim3(BB), dim3(1024), 0, stream>>>(pp);

    // logits: hallb[6656,512] @ Woutb^T + bout -> out[b,t,:], then log-softmax
    gemm_mfma<0, 1><<<dim3(40, 52), dim3(256), 0, stream>>>(
        hallb, Woutb, bout, out, nullptr, nullptr, TT * BB, V);
    logsoftmax_rows<<<dim3(BB * TT), dim3(256), 0, stream>>>(out);
}

// Round 18
// 1257.451 us; speedup vs baseline: 2.1879x; 1.5964x over previous
//
#include <hip/hip_runtime.h>
#include <math.h>

#define H 512
#define V 5000
#define BB 128
#define SS 64
#define TT 52
#define GSZ 16      // blocks per group = batches per group
#define NBLK 128    // persistent blocks (co-residency proven at 160)
#define LROWS 96    // weight rows LDS-staged per block (of 160)

typedef __attribute__((ext_vector_type(8))) short bf16x8;
typedef __attribute__((ext_vector_type(4))) float f32x4;
typedef __attribute__((ext_vector_type(2))) float f32x2;

__device__ __forceinline__ unsigned short f2b(float f) {
    unsigned u = __float_as_uint(f);
    return (unsigned short)((u + 0x7fffu + ((u >> 16) & 1u)) >> 16);
}
__device__ __forceinline__ float b2f(unsigned short u) {
    return __uint_as_float((unsigned)u << 16);
}
__device__ __forceinline__ float ftanh(float x) {
    return 1.f - 2.f / (1.f + __expf(2.f * x));
}
__device__ __forceinline__ float fsig(float x) {
    return 1.f / (1.f + __expf(-x));
}
__device__ __forceinline__ unsigned char f2fp8(float f) {
    return (unsigned char)__builtin_amdgcn_cvt_pk_fp8_f32(f, f, 0, 0);
}

// ---------------------------------------------------------------------------
// Cross-block coherent accesses: sc0 sc1 ONLY (L3 coherence point; proven
// r4-r10). LESSON r12/r13: sc0-only loads do NOT bypass L1 on gfx950.
// ---------------------------------------------------------------------------
__device__ __forceinline__ void pollf(unsigned* a, unsigned s)
{
    for (;;) {
        unsigned v;
        asm volatile("global_load_dword %0, %1, off sc0 sc1\n\ts_waitcnt vmcnt(0)"
                     : "=v"(v) : "v"(a) : "memory");
        if (v >= s) break;
        __builtin_amdgcn_s_sleep(1);
    }
}
__device__ __forceinline__ void fst(unsigned* p, unsigned v)
{
    asm volatile("global_store_dword %0, %1, off sc0 sc1" :: "v"(p), "v"(v) : "memory");
}
__device__ __forceinline__ void cstf4(float* p, f32x4 v)
{
    asm volatile("global_store_dwordx4 %0, %1, off sc0 sc1" :: "v"(p), "v"(v) : "memory");
}
__device__ __forceinline__ void cld4x16B(const unsigned short* p0, const unsigned short* p1,
                                         const unsigned short* p2, const unsigned short* p3,
                                         uint4& a, uint4& b, uint4& c, uint4& d)
{
    asm volatile(
        "global_load_dwordx4 %0, %4, off sc0 sc1\n\t"
        "global_load_dwordx4 %1, %5, off sc0 sc1\n\t"
        "global_load_dwordx4 %2, %6, off sc0 sc1\n\t"
        "global_load_dwordx4 %3, %7, off sc0 sc1\n\t"
        "s_waitcnt vmcnt(0)"
        : "=v"(a), "=v"(b), "=v"(c), "=v"(d)
        : "v"(p0), "v"(p1), "v"(p2), "v"(p3) : "memory");
}
__device__ __forceinline__ void cldf2(const float* p0, const float* p1, float& a, float& b)
{
    asm volatile(
        "global_load_dword %0, %2, off sc0 sc1\n\t"
        "global_load_dword %1, %3, off sc0 sc1\n\t"
        "s_waitcnt vmcnt(0)"
        : "=v"(a), "=v"(b) : "v"(p0), "v"(p1) : "memory");
}
// 8 strided f32 loads (stride GSZ f32 = 64B), one wait (Ybuf gate rows).
__device__ __forceinline__ void cldf8s(const float* p, float* r)
{
    asm volatile(
        "global_load_dword %0, %8, off sc0 sc1\n\t"
        "global_load_dword %1, %8, off offset:64 sc0 sc1\n\t"
        "global_load_dword %2, %8, off offset:128 sc0 sc1\n\t"
        "global_load_dword %3, %8, off offset:192 sc0 sc1\n\t"
        "global_load_dword %4, %8, off offset:256 sc0 sc1\n\t"
        "global_load_dword %5, %8, off offset:320 sc0 sc1\n\t"
        "global_load_dword %6, %8, off offset:384 sc0 sc1\n\t"
        "global_load_dword %7, %8, off offset:448 sc0 sc1\n\t"
        "s_waitcnt vmcnt(0)"
        : "=v"(r[0]), "=v"(r[1]), "=v"(r[2]), "=v"(r[3]),
          "=v"(r[4]), "=v"(r[5]), "=v"(r[6]), "=v"(r[7])
        : "v"(p) : "memory");
}
__device__ __forceinline__ void cstu32c(unsigned* p, unsigned v)
{
    asm volatile("global_store_dword %0, %1, off sc0 sc1" :: "v"(p), "v"(v) : "memory");
}

// ---------------------------------------------------------------------------
// prep: Whb [2560][512] = [Wa ; W_hh], Wxb [2048][512] = W_ih[:, :512],
// Wc [2048][512] = W_ih[:, 512:], bbig = [ba ; b_ih+b_hh], bf16 Ua/Wout/enc.
// ---------------------------------------------------------------------------
__global__ __launch_bounds__(256)
void prep_w(const float* __restrict__ Wa, const float* __restrict__ Whh,
            const float* __restrict__ Wih,
            const float* __restrict__ ba, const float* __restrict__ bih,
            const float* __restrict__ bhh,
            const float* __restrict__ Ua, const float* __restrict__ Wout,
            const float* __restrict__ enc,
            unsigned short* __restrict__ Whb, unsigned short* __restrict__ Wxb,
            unsigned short* __restrict__ Wc,
            unsigned short* __restrict__ Uab, unsigned short* __restrict__ Woutb,
            unsigned short* __restrict__ encb, float* __restrict__ bbig)
{
    const int stride = gridDim.x * blockDim.x;
    const int t0 = blockIdx.x * blockDim.x + threadIdx.x;
    for (int idx = t0; idx < 2560 * 512; idx += stride) {
        const int j = idx >> 9, k = idx & 511;
        Whb[idx] = f2b((j < H) ? Wa[j * H + k] : Whh[(j - H) * H + k]);
    }
    for (int idx = t0; idx < 2048 * 512; idx += stride) {
        const int n = idx >> 9, k = idx & 511;
        Wxb[idx] = f2b(Wih[n * 2 * H + k]);
        Wc[idx]  = f2b(Wih[n * 2 * H + H + k]);
    }
    for (int idx = t0; idx < 512 * 512; idx += stride)   Uab[idx]   = f2b(Ua[idx]);
    for (int idx = t0; idx < V * 512; idx += stride)     Woutb[idx] = f2b(Wout[idx]);
    for (int idx = t0; idx < BB * SS * H; idx += stride) encb[idx]  = f2b(enc[idx]);
    for (int j = t0; j < 2560; j += stride)
        bbig[j] = (j < H) ? ba[j] : bih[j - H] + bhh[j - H];
}

__global__ __launch_bounds__(256)
void gather_x(const float* __restrict__ emb, const int* __restrict__ tgt,
              unsigned short* __restrict__ xall)
{
    const int stride = gridDim.x * blockDim.x;
    for (int idx = blockIdx.x * blockDim.x + threadIdx.x; idx < TT * BB * H; idx += stride) {
        const int k = idx & 511;
        const int row = idx >> 9;
        const int t = row >> 7, b = row & 127;
        const int tok = (t == 0) ? 0 : tgt[b * TT + t - 1];
        xall[idx] = f2b(emb[(size_t)tok * H + k]);
    }
}

// ---------------------------------------------------------------------------
// bf16 MFMA NT-GEMM, K=512. OUT_MODE: 0=f32 (+PERMUTE r=t*B+b -> b*T+t),
// 1=bf16, 2=fp8. Used for keysb, encW8, xgates, logits.
// ---------------------------------------------------------------------------
template<int OUT_MODE, int PERMUTE>
__global__ __launch_bounds__(256, 2)
void gemm_mfma(const unsigned short* __restrict__ A,
               const unsigned short* __restrict__ B,
               const float* __restrict__ bias,
               float* __restrict__ Cf, unsigned short* __restrict__ Cb,
               unsigned char* __restrict__ C8,
               int M, int N)
{
    __shared__ unsigned short As[128][72];
    __shared__ unsigned short Bs[128][72];
    const int tid = threadIdx.x;
    const int m0 = blockIdx.y * 128, n0 = blockIdx.x * 128;
    const int lane = tid & 63, wv = tid >> 6;
    const int qm = (wv >> 1) * 64, qn = (wv & 1) * 64;
    const int fr = lane & 15, fg = lane >> 4;
    f32x4 acc[4][4];
#pragma unroll
    for (int i = 0; i < 4; ++i)
#pragma unroll
        for (int j = 0; j < 4; ++j) acc[i][j] = (f32x4){0.f, 0.f, 0.f, 0.f};

    const int srow = tid >> 3, sc = (tid & 7) * 8;
    for (int k0 = 0; k0 < H; k0 += 64) {
#pragma unroll
        for (int u = 0; u < 4; ++u) {
            const int row = srow + u * 32;
            *(uint4*)&As[row][sc] = *(const uint4*)&A[(size_t)(m0 + row) * H + k0 + sc];
            int nr = n0 + row; if (nr > N - 1) nr = N - 1;
            *(uint4*)&Bs[row][sc] = *(const uint4*)&B[(size_t)nr * H + k0 + sc];
        }
        __syncthreads();
#pragma unroll
        for (int ks = 0; ks < 2; ++ks) {
            const int kk = ks * 32 + fg * 8;
            bf16x8 av[4], bv[4];
#pragma unroll
            for (int i = 0; i < 4; ++i) {
                av[i] = *(const bf16x8*)&As[qm + i * 16 + fr][kk];
                bv[i] = *(const bf16x8*)&Bs[qn + i * 16 + fr][kk];
            }
#pragma unroll
            for (int i = 0; i < 4; ++i)
#pragma unroll
                for (int j = 0; j < 4; ++j)
                    acc[i][j] = __builtin_amdgcn_mfma_f32_16x16x32_bf16(av[i], bv[j], acc[i][j], 0, 0, 0);
        }
        __syncthreads();
    }
#pragma unroll
    for (int i = 0; i < 4; ++i) {
        const int r0 = m0 + qm + i * 16 + fg * 4;
#pragma unroll
        for (int j = 0; j < 4; ++j) {
            const int col = n0 + qn + j * 16 + fr;
            if (col < N) {
                const float bi = bias ? bias[col] : 0.f;
#pragma unroll
                for (int v = 0; v < 4; ++v) {
                    const int r = r0 + v;
                    const float val = acc[i][j][v] + bi;
                    if (OUT_MODE == 1) Cb[(size_t)r * N + col] = f2b(val);
                    else if (OUT_MODE == 2) C8[(size_t)r * N + col] = f2fp8(val);
                    else {
                        const size_t orow = PERMUTE ? ((size_t)(r & (BB - 1)) * TT + (r >> 7))
                                                    : (size_t)r;
                        Cf[orow * (size_t)N + col] = val;
                    }
                }
            }
        }
    }
}

struct PParams {
    const float* h0;
    const float* c0;
    const unsigned short* keysb;   // [B*S][512] bf16 (plain cached)
    const unsigned char* encW8;    // [B*S][2048] fp8 (plain cached)
    const float* Va;
    const float* bv;
    const float* bbig;             // [2560]
    const unsigned short* Whb;     // [2560][512] bf16 (plain cached)
    const unsigned short* xgates;  // [T*B][2048] bf16 (plain cached)
    unsigned short* hbuf;          // [8][16][512] bf16 -- sc0sc1 exchanged
    float* Ybuf;                   // [8][2560][16] f32 -- sc0sc1 exchanged
    unsigned short* hallb;         // [T*B][512] bf16 (plain; next dispatch)
    float* attn;
    float* out_h;
    float* out_c;
    unsigned* hfl;                 // [128*32]
    unsigned* yfl;                 // [128*32]
};

// ---------------------------------------------------------------------------
// Persistent kernel (r14 structure + latency-hiding prefetches):
//  P1: PREFETCH this wave's streamed weight tile (step-invariant rows) into
//      regs BEFORE the h-wait (r14's 64 streamed rows missed L2 every step,
//      ~1MB/XCD/step of exposed HBM latency inside the phase = the bulk of
//      the 20us step) -> wait 16 hfl -> h_s -> 6 LDS-tile MFMAs + 1
//      reg-tile MFMA -> Y col-major stores -> yfl.
//  P2: PREFETCH keysb slice (b-static) before the qa wait -> qa -> scores/
//      softmax -> encW8 sum -> wait 16 yfl -> gates + xgates + LSTM -> hfl.
// ---------------------------------------------------------------------------
__global__ __launch_bounds__(256, 1)
void persist(PParams p)
{
    __shared__ unsigned short WA[LROWS][520];
    __shared__ unsigned short h_s[16][520];
    __shared__ float qa_s[H];
    __shared__ float va_s[H];
    __shared__ float part[SS][4];
    __shared__ float wbuf[SS];
    __shared__ float gbuf[4 * H];
    __shared__ float cs[H];

    const int tid  = threadIdx.x;
    const int beta = blockIdx.x;
    const int grp  = beta & 7;
    const int slot = beta >> 3;
    const int gb   = grp * GSZ + slot;
    const int gi   = gb;
    const int wv   = tid >> 6, lane = tid & 63;
    const int fr   = lane & 15, fg = lane >> 4;

    unsigned short* hbg = p.hbuf + (size_t)grp * GSZ * H;
    float* ybg = p.Ybuf + (size_t)grp * 2560 * GSZ;

    // ---- prologue: stage weights, init per-batch state, publish h0 ----
    for (int idx = tid; idx < LROWS * 64; idx += 256) {
        const int r = idx >> 6, c = idx & 63;
        *(uint4*)&WA[r][c * 8] =
            *(const uint4*)&p.Whb[((size_t)slot * 160 + r) * H + c * 8];
    }
    for (int j = tid; j < H; j += 256) {
        cs[j] = p.c0[(size_t)gb * H + j];
        va_s[j] = p.Va[j];
    }
    {
        const float* hp = p.h0 + (size_t)gb * H;
        const unsigned hp32 = (unsigned)f2b(hp[tid * 2]) |
                              ((unsigned)f2b(hp[tid * 2 + 1]) << 16);
        cstu32c((unsigned*)(hbg + (size_t)slot * H) + tid, hp32);
    }
    __syncthreads();   // drain h0 stores (vmcnt 0) + LDS staging
    if (tid == 0) fst(&p.hfl[gi * 32], 1u);

    for (int t = 0; t < TT; ++t) {
        const unsigned st = (unsigned)(t + 1);
        // ---------------- P1 ----------------
        // prefetch this wave's streamed weight tile BEFORE the h-wait:
        // rows are step-invariant, so the L2/HBM miss latency overlaps the
        // producer wait instead of sitting inside the phase.
        const int tts = (wv < 2) ? (wv + 8) : (wv + 4);   // tiles 8,9,6,7
        bf16x8 wr[16];
        {
            const unsigned short* wrow =
                p.Whb + ((size_t)slot * 160 + tts * 16 + fr) * H + fg * 8;
#pragma unroll
            for (int ks = 0; ks < 16; ++ks)
                wr[ks] = *(const bf16x8*)&wrow[ks * 32];
        }
        if (tid < GSZ) pollf(&p.hfl[(grp * GSZ + tid) * 32], st);
        __syncthreads();
        {   // h_s <- hbg (4 x 16B per thread, single wait)
            uint4 a, b, c4, d;
            cld4x16B(hbg + (size_t)tid * 8, hbg + (size_t)(tid + 256) * 8,
                     hbg + (size_t)(tid + 512) * 8, hbg + (size_t)(tid + 768) * 8,
                     a, b, c4, d);
            const int r0 = tid >> 6, c0 = (tid & 63) * 8;
            *(uint4*)&h_s[r0][c0]      = a;
            *(uint4*)&h_s[r0 + 4][c0]  = b;
            *(uint4*)&h_s[r0 + 8][c0]  = c4;
            *(uint4*)&h_s[r0 + 12][c0] = d;
        }
        __syncthreads();
        for (int tt = wv; tt < 6; tt += 4) {          // LDS tiles 0..5
            const int jrow = slot * 160 + tt * 16 + fr;
            f32x4 acc = {0.f, 0.f, 0.f, 0.f};
#pragma unroll
            for (int ks = 0; ks < 16; ++ks) {
                bf16x8 A = *(const bf16x8*)&h_s[fr][ks * 32 + fg * 8];
                bf16x8 B = *(const bf16x8*)&WA[tt * 16 + fr][ks * 32 + fg * 8];
                acc = __builtin_amdgcn_mfma_f32_16x16x32_bf16(A, B, acc, 0, 0, 0);
            }
            const float bb = p.bbig[jrow];
            f32x4 o;
#pragma unroll
            for (int i = 0; i < 4; ++i) o[i] = acc[i] + bb;
            cstf4(ybg + (size_t)jrow * GSZ + fg * 4, o);
        }
        {   // streamed tile from prefetched registers
            const int jrow = slot * 160 + tts * 16 + fr;
            f32x4 acc = {0.f, 0.f, 0.f, 0.f};
#pragma unroll
            for (int ks = 0; ks < 16; ++ks) {
                bf16x8 A = *(const bf16x8*)&h_s[fr][ks * 32 + fg * 8];
                acc = __builtin_amdgcn_mfma_f32_16x16x32_bf16(A, wr[ks], acc, 0, 0, 0);
            }
            const float bb = p.bbig[jrow];
            f32x4 o;
#pragma unroll
            for (int i = 0; i < 4; ++i) o[i] = acc[i] + bb;
            cstf4(ybg + (size_t)jrow * GSZ + fg * 4, o);
        }
        __syncthreads();   // drain Y stores
        if (tid == 0) fst(&p.yfl[gi * 32], st);

        // ---------------- P2 ----------------
        // prefetch the scores operand (b-static keysb slice) before qa wait
        bf16x8 kr[16];
        {
            const unsigned short* kp0 =
                p.keysb + ((size_t)gb * SS + (tid >> 2)) * H + (tid & 3) * 128;
#pragma unroll
            for (int i8 = 0; i8 < 16; ++i8)
                kr[i8] = *(const bf16x8*)&kp0[i8 * 8];
        }
        if (tid < 4) pollf(&p.yfl[(grp * GSZ + tid) * 32], st);   // qa rows 0-511
        __syncthreads();
        cldf2(ybg + (size_t)tid * GSZ + slot,
              ybg + (size_t)(tid + 256) * GSZ + slot,
              qa_s[tid], qa_s[tid + 256]);
        __syncthreads();
        {   // scores from prefetched keys, 2-way ILP tanh chain
            const int s = tid >> 2, q = tid & 3;
            const float* qp = qa_s + q * 128;
            const float* vp = va_s + q * 128;
            float a2 = 0.f, a2b = 0.f;
#pragma unroll
            for (int i8 = 0; i8 < 16; ++i8) {
                bf16x8 kv = kr[i8];
#pragma unroll
                for (int u = 0; u < 8; u += 2) {
                    const int i = i8 * 8 + u;
                    a2  += ftanh(qp[i]     + b2f((unsigned short)kv[u]))     * vp[i];
                    a2b += ftanh(qp[i + 1] + b2f((unsigned short)kv[u + 1])) * vp[i + 1];
                }
            }
            part[s][q] = a2 + a2b;
        }
        __syncthreads();
        if (tid < 64) {
            float sc = part[tid][0] + part[tid][1] + part[tid][2] + part[tid][3] + p.bv[0];
            float m = sc;
            for (int o = 32; o; o >>= 1) m = fmaxf(m, __shfl_xor(m, o));
            const float e = __expf(sc - m);
            float ss = e;
            for (int o = 32; o; o >>= 1) ss += __shfl_xor(ss, o);
            const float w = e / ss;
            wbuf[tid] = w;
            p.attn[((size_t)gb * TT + t) * SS + tid] = w;
        }
        __syncthreads();
        float gc[8] = {0.f, 0.f, 0.f, 0.f, 0.f, 0.f, 0.f, 0.f};
        {   // encW8 weighted sum FIRST (needs only wbuf) -> gate-producer slack
            const unsigned char* ew = p.encW8 + (size_t)gb * SS * 2048 + tid * 8;
#pragma unroll 8
            for (int s2 = 0; s2 < SS; ++s2) {
                const float w2 = wbuf[s2];
                const uint2 u = *(const uint2*)(ew + (size_t)s2 * 2048);
                const f32x2 e01 = __builtin_amdgcn_cvt_pk_f32_fp8(u.x, 0);
                const f32x2 e23 = __builtin_amdgcn_cvt_pk_f32_fp8(u.x, 1);
                const f32x2 e45 = __builtin_amdgcn_cvt_pk_f32_fp8(u.y, 0);
                const f32x2 e67 = __builtin_amdgcn_cvt_pk_f32_fp8(u.y, 1);
                gc[0] += w2 * e01[0]; gc[1] += w2 * e01[1];
                gc[2] += w2 * e23[0]; gc[3] += w2 * e23[1];
                gc[4] += w2 * e45[0]; gc[5] += w2 * e45[1];
                gc[6] += w2 * e67[0]; gc[7] += w2 * e67[1];
            }
        }
        if (tid < GSZ) pollf(&p.yfl[(grp * GSZ + tid) * 32], st);  // gate rows
        __syncthreads();
        {   // gates = gc + Y gate rows + xgates
            float yg[8];
            cldf8s(ybg + (size_t)(512 + tid * 8) * GSZ + slot, yg);
            bf16x8 xg = *(const bf16x8*)&p.xgates[((size_t)t * BB + gb) * 2048 + tid * 8];
#pragma unroll
            for (int i = 0; i < 8; ++i)
                gbuf[tid * 8 + i] = gc[i] + yg[i] + b2f((unsigned short)xg[i]);
        }
        __syncthreads();
        {   // LSTM: cells 2*tid, 2*tid+1
            const int last = (t == TT - 1);
            unsigned hpack = 0;
            float hn2[2], cn2[2];
#pragma unroll
            for (int u = 0; u < 2; ++u) {
                const int j = tid * 2 + u;
                const float ig  = gbuf[j];
                const float fgt = gbuf[512 + j];
                const float gg  = gbuf[1024 + j];
                const float og  = gbuf[1536 + j];
                const float co  = cs[j];
                const float cn = fsig(fgt) * co + fsig(ig) * ftanh(gg);
                const float hn = fsig(og) * ftanh(cn);
                cs[j] = cn;
                hn2[u] = hn; cn2[u] = cn;
                hpack |= ((unsigned)f2b(hn)) << (16 * u);
            }
            cstu32c((unsigned*)(hbg + (size_t)slot * H) + tid, hpack);
            *(unsigned*)&p.hallb[((size_t)t * BB + gb) * H + tid * 2] = hpack;
            if (last) {
#pragma unroll
                for (int u = 0; u < 2; ++u) {
                    p.out_h[gb * H + tid * 2 + u] = hn2[u];
                    p.out_c[gb * H + tid * 2 + u] = cn2[u];
                }
            }
        }
        __syncthreads();   // drain h stores
        if (tid == 0) fst(&p.hfl[gi * 32], st + 1);
    }
}

// ---------------------------------------------------------------------------
// In-place log-softmax over each row of 5000 logits.
// ---------------------------------------------------------------------------
__global__ __launch_bounds__(256)
void logsoftmax_rows(float* __restrict__ P)
{
    __shared__ float red[256];
    float* p = P + (size_t)blockIdx.x * V;
    const int tid = threadIdx.x;
    float m = -1e30f;
    for (int i = tid; i < V; i += 256) m = fmaxf(m, p[i]);
    red[tid] = m; __syncthreads();
    for (int sft = 128; sft; sft >>= 1) {
        if (tid < sft) red[tid] = fmaxf(red[tid], red[tid + sft]);
        __syncthreads();
    }
    m = red[0]; __syncthreads();
    float ssum = 0.f;
    for (int i = tid; i < V; i += 256) ssum += __expf(p[i] - m);
    red[tid] = ssum; __syncthreads();
    for (int sft = 128; sft; sft >>= 1) {
        if (tid < sft) red[tid] += red[tid + sft];
        __syncthreads();
    }
    const float lse = m + __logf(red[0]);
    for (int i = tid; i < V; i += 256) p[i] -= lse;
}

// ---------------------------------------------------------------------------
extern "C" void kernel_launch(void* const* d_in, const int* in_sizes, int n_in,
                              void* d_out, int out_size, void* d_ws, size_t ws_size,
                              hipStream_t stream)
{
    (void)in_sizes; (void)n_in; (void)out_size; (void)ws_size;
    const float* enc  = (const float*)d_in[0];
    const float* h0   = (const float*)d_in[1];
    const float* c0   = (const float*)d_in[2];
    const int*   tgt  = (const int*)  d_in[3];
    const float* emb  = (const float*)d_in[4];
    const float* Wa   = (const float*)d_in[5];
    const float* ba   = (const float*)d_in[6];
    const float* Ua   = (const float*)d_in[7];
    const float* bu   = (const float*)d_in[8];
    const float* Va   = (const float*)d_in[9];
    const float* bv   = (const float*)d_in[10];
    const float* Wih  = (const float*)d_in[11];
    const float* Whh  = (const float*)d_in[12];
    const float* bih  = (const float*)d_in[13];
    const float* bhh  = (const float*)d_in[14];
    const float* Wout = (const float*)d_in[15];
    const float* bout = (const float*)d_in[16];

    float* ws = (float*)d_ws;
    float* bbig = ws;                                      // 2,560 f32
    float* Ybuf = bbig + 2560;                             // 327,680 f32
    unsigned* flags = (unsigned*)(Ybuf + 327680);          // 8,192 u32
    unsigned* hfl = flags;                                 // 128*32
    unsigned* yfl = flags + 4096;                          // 128*32
    unsigned short* Whb   = (unsigned short*)(flags + 8192);   // 1,310,720 u16
    unsigned short* Wxb   = Whb + 1310720;                 // 1,048,576
    unsigned short* Wc    = Wxb + 1048576;                 // 1,048,576
    unsigned short* Uab   = Wc + 1048576;                  // 262,144
    unsigned short* Woutb = Uab + 262144;                  // 2,560,000
    unsigned short* encb  = Woutb + 2560000;               // 4,194,304
    unsigned short* keysb = encb + 4194304;                // 4,194,304
    unsigned short* xall  = keysb + 4194304;               // 3,407,872
    unsigned short* xgates= xall + 3407872;                // 13,631,488
    unsigned short* hallb = xgates + 13631488;             // 3,407,872
    unsigned short* hbuf  = hallb + 3407872;               // 65,536
    unsigned char*  encW8 = (unsigned char*)(hbuf + 65536); // 16,777,216 u8

    float* out    = (float*)d_out;
    float* out_h  = out + (size_t)BB * TT * V;
    float* out_c  = out_h + BB * H;
    float* out_at = out_c + BB * H;

    hipMemsetAsync(flags, 0, 8192 * sizeof(unsigned), stream);

    prep_w<<<dim3(2048), dim3(256), 0, stream>>>(
        Wa, Whh, Wih, ba, bih, bhh, Ua, Wout, enc,
        Whb, Wxb, Wc, Uab, Woutb, encb, bbig);
    gather_x<<<dim3(512), dim3(256), 0, stream>>>(emb, tgt, xall);

    // keys_proj = enc @ Ua^T + bu -> bf16 [8192,512]
    gemm_mfma<1, 0><<<dim3(4, 64), dim3(256), 0, stream>>>(
        encb, Uab, bu, nullptr, keysb, nullptr, BB * SS, H);
    // encW8 = enc @ Wc^T -> fp8 [8192,2048]
    gemm_mfma<2, 0><<<dim3(16, 64), dim3(256), 0, stream>>>(
        encb, Wc, nullptr, nullptr, nullptr, encW8, BB * SS, 2048);
    // xgates = x @ Wx^T -> bf16 [6656,2048]  (teacher-forced x-part, hoisted)
    gemm_mfma<1, 0><<<dim3(16, 52), dim3(256), 0, stream>>>(
        xall, Wxb, nullptr, nullptr, xgates, nullptr, TT * BB, 2048);

    PParams pp;
    pp.h0 = h0; pp.c0 = c0; pp.keysb = keysb; pp.encW8 = encW8;
    pp.Va = Va; pp.bv = bv; pp.bbig = bbig;
    pp.Whb = Whb; pp.xgates = xgates;
    pp.hbuf = hbuf; pp.Ybuf = Ybuf; pp.hallb = hallb;
    pp.attn = out_at; pp.out_h = out_h; pp.out_c = out_c;
    pp.hfl = hfl; pp.yfl = yfl;
    persist<<<dim3(NBLK), dim3(256), 0, stream>>>(pp);

    // logits: hallb[6656,512] @ Woutb^T + bout -> out[b,t,:], then log-softmax
    gemm_mfma<0, 1><<<dim3(40, 52), dim3(256), 0, stream>>>(
        hallb, Woutb, bout, out, nullptr, nullptr, TT * BB, V);
    logsoftmax_rows<<<dim3(BB * TT), dim3(256), 0, stream>>>(out);
}